// Round 1
// baseline (271.984 us; speedup 1.0000x reference)
//
#include <hip/hip_runtime.h>
#include <hip/hip_bf16.h>
#include <math.h>

typedef unsigned long long u64;
typedef unsigned char u8;
typedef unsigned short u16;
typedef unsigned int u32;

#define BB 8
#define CC 19
#define HH 512
#define WW 512
#define HWSZ (HH*WW)
#define NIMG 16

// ---------------------------------------------------------------------------
// 1) argmax over channel dim -> img_p = (cls*255)%256 = (u8)(-cls)
// ---------------------------------------------------------------------------
__global__ __launch_bounds__(256) void k_argmax(const float* __restrict__ pred,
                                                u8* __restrict__ img) {
    int idx = blockIdx.x * 256 + threadIdx.x;   // 4 pixels per thread
    int p4 = idx * 4;
    int b = p4 / HWSZ;
    int rem = p4 - b * HWSZ;
    const float4* base = (const float4*)(pred + (size_t)b * CC * HWSZ + rem);
    float4 best = base[0];
    int ix = 0, iy = 0, iz = 0, iw = 0;
    for (int c = 1; c < CC; ++c) {
        float4 v = base[(size_t)c * (HWSZ / 4)];
        if (v.x > best.x) { best.x = v.x; ix = c; }
        if (v.y > best.y) { best.y = v.y; iy = c; }
        if (v.z > best.z) { best.z = v.z; iz = c; }
        if (v.w > best.w) { best.w = v.w; iw = c; }
    }
    uchar4 o;
    o.x = (u8)(-ix); o.y = (u8)(-iy); o.z = (u8)(-iz); o.w = (u8)(-iw);
    *(uchar4*)(img + p4) = o;
}

// ---------------------------------------------------------------------------
// 2) img_l = floor(labels*255), labels in [0,1)
// ---------------------------------------------------------------------------
__global__ __launch_bounds__(256) void k_imgl(const float* __restrict__ lab,
                                              u8* __restrict__ img) {
    int idx = blockIdx.x * 256 + threadIdx.x;
    int p4 = idx * 4;
    float4 v = *(const float4*)(lab + p4);
    uchar4 o;
    o.x = (u8)(v.x * 255.0f);
    o.y = (u8)(v.y * 255.0f);
    o.z = (u8)(v.z * 255.0f);
    o.w = (u8)(v.w * 255.0f);
    *(uchar4*)(img + p4) = o;
}

// ---------------------------------------------------------------------------
// 3) Sobel (edge-replicate pad) + L1 mag + quantized direction.
//    magdir = mag (12 bits, <=2040) | dir<<12, dir in {0:0deg,1:45,2:90,3:135}
// ---------------------------------------------------------------------------
__global__ __launch_bounds__(256) void k_grad(const u8* __restrict__ imgs,
                                              u16* __restrict__ magdir) {
    int t = blockIdx.x * 256 + threadIdx.x;     // 8 pixels per thread
    int x0 = (t & 63) * 8;
    int y  = (t >> 6) & 511;
    int im = t >> 15;
    const u8* base = imgs + (size_t)im * HWSZ;
    int rows[3];
    rows[0] = (y == 0) ? 0 : y - 1;
    rows[1] = y;
    rows[2] = (y == 511) ? 511 : y + 1;
    int bb[3][10];
#pragma unroll
    for (int r = 0; r < 3; ++r) {
        const u8* rp = base + rows[r] * WW;
        u64 m = *(const u64*)(rp + x0);
        bb[r][0] = (x0 == 0) ? rp[0] : rp[x0 - 1];
#pragma unroll
        for (int i = 0; i < 8; ++i) bb[r][i + 1] = (int)((m >> (8 * i)) & 0xFF);
        bb[r][9] = (x0 == 504) ? rp[511] : rp[x0 + 8];
    }
    u32 v[8];
#pragma unroll
    for (int i = 0; i < 8; ++i) {
        int a00 = bb[0][i], a01 = bb[0][i + 1], a02 = bb[0][i + 2];
        int a10 = bb[1][i],                     a12 = bb[1][i + 2];
        int a20 = bb[2][i], a21 = bb[2][i + 1], a22 = bb[2][i + 2];
        int gx = (a02 + 2 * a12 + a22) - (a00 + 2 * a10 + a20);
        int gy = (a20 + 2 * a21 + a22) - (a00 + 2 * a01 + a02);
        int ax = gx < 0 ? -gx : gx;
        int ay = gy < 0 ? -gy : gy;
        int mag = ax + ay;
        float fax = (float)ax, fay = (float)ay;
        int dir;
        if (fay < 0.41421356237309515f * fax) dir = 0;           // <22.5 or >=157.5
        else if (fay >= 2.414213562373095f * fax) dir = 2;       // [67.5,112.5)
        else dir = ((gx ^ gy) >= 0) ? 1 : 3;                     // 45 : 135
        v[i] = (u32)mag | ((u32)dir << 12);
    }
    uint4 o;
    o.x = v[0] | (v[1] << 16);
    o.y = v[2] | (v[3] << 16);
    o.z = v[4] | (v[5] << 16);
    o.w = v[6] | (v[7] << 16);
    *(uint4*)(magdir + (size_t)im * HWSZ + y * WW + x0) = o;
}

// ---------------------------------------------------------------------------
// 4) NMS + double threshold -> bit-packed weak/strong (zero mag outside image)
// ---------------------------------------------------------------------------
__global__ __launch_bounds__(256) void k_nms(const u16* __restrict__ magdir,
                                             u64* __restrict__ weak,
                                             u64* __restrict__ strong) {
    int t = blockIdx.x * 256 + threadIdx.x;     // one pixel per thread
    int x  = t & 511;
    int y  = (t >> 9) & 511;
    int im = t >> 18;
    const u16* md = magdir + (size_t)im * HWSZ;
    u32 v = md[y * WW + x];
    int mag = v & 0xFFF;
    int dir = v >> 12;
    auto M = [&](int yy, int xx) -> int {
        if ((unsigned)yy > 511u || (unsigned)xx > 511u) return 0;
        return md[yy * WW + xx] & 0xFFF;
    };
    int n1, n2;
    switch (dir) {
        case 0:  n1 = M(y, x - 1);     n2 = M(y, x + 1);     break;
        case 1:  n1 = M(y - 1, x + 1); n2 = M(y + 1, x - 1); break;
        case 2:  n1 = M(y - 1, x);     n2 = M(y + 1, x);     break;
        default: n1 = M(y - 1, x - 1); n2 = M(y + 1, x + 1); break;
    }
    bool keep = (mag >= n1) && (mag >= n2);
    u64 wb = __ballot(keep && mag > 100);
    u64 sb = __ballot(keep && mag > 200);
    if ((threadIdx.x & 63) == 0) {
        size_t w = ((size_t)im * HH + y) * 8 + (x >> 6);
        weak[w] = wb;
        strong[w] = sb;
    }
}

// ---------------------------------------------------------------------------
// 5) hysteresis to fixed point (capped 256 iters = reference recurrence).
//    One block per image; one row (8 u64) per thread; h = horizontally
//    dilated rows staged in LDS; Jacobi update matches reference exactly.
// ---------------------------------------------------------------------------
__global__ __launch_bounds__(512) void k_hyst(const u64* __restrict__ weakg,
                                              const u64* __restrict__ strongg,
                                              u64* __restrict__ edges) {
    __shared__ u64 h[512][8];
    __shared__ int flags[2];
    int y = threadIdx.x;
    int im = blockIdx.x;
    size_t base = ((size_t)im * HH + y) * 8;
    u64 wk[8], st[8], s[8];
#pragma unroll
    for (int j = 0; j < 8; ++j) {
        wk[j] = weakg[base + j];
        st[j] = strongg[base + j];
        s[j] = st[j];
    }
    for (int it = 0; it < 256; ++it) {
        u64 hh[8];
#pragma unroll
        for (int j = 0; j < 8; ++j) hh[j] = s[j] | (s[j] << 1) | (s[j] >> 1);
#pragma unroll
        for (int j = 1; j < 8; ++j) hh[j] |= s[j - 1] >> 63;
#pragma unroll
        for (int j = 0; j < 7; ++j) hh[j] |= s[j + 1] << 63;
#pragma unroll
        for (int j = 0; j < 8; ++j) h[y][j] = hh[j];
        if (threadIdx.x == 0 && it == 0) flags[0] = 0;
        __syncthreads();                              // sync1
        if (threadIdx.x == 0) flags[(it + 1) & 1] = 0;
        int changed = 0;
#pragma unroll
        for (int j = 0; j < 8; ++j) {
            u64 up = (y > 0)   ? h[y - 1][j] : 0ull;
            u64 dn = (y < 511) ? h[y + 1][j] : 0ull;
            u64 ns = (wk[j] & (hh[j] | up | dn)) | st[j];
            changed |= (ns != s[j]);
            s[j] = ns;
        }
        if (changed) flags[it & 1] = 1;
        __syncthreads();                              // sync2
        if (!flags[it & 1]) break;
    }
#pragma unroll
    for (int j = 0; j < 8; ++j) edges[base + j] = s[j];
}

// ---------------------------------------------------------------------------
// 6) loss. Per column (b,w): k = popcount(ep col), Z = 512 + (e-1)*k,
//    col = elsum*log(Z) - overlap; out = mean over 4096 columns.
// ---------------------------------------------------------------------------
__global__ void k_zero(float* out) {
    if (threadIdx.x == 0 && blockIdx.x == 0) out[0] = 0.0f;
}

__global__ __launch_bounds__(256) void k_loss(const u64* __restrict__ edges,
                                              float* __restrict__ out) {
    int b = blockIdx.x >> 3;        // image pair index
    int j = blockIdx.x & 7;         // word column
    int wave = threadIdx.x >> 6;
    int lane = threadIdx.x & 63;
    const u64* ep = edges + ((size_t)b * HH) * 8 + j;
    const u64* el = edges + ((size_t)(b + 8) * HH) * 8 + j;
    int k = 0, es = 0, ov = 0;
    int y0 = wave * 128;
    for (int y = y0; y < y0 + 128; ++y) {
        u64 wp = ep[(size_t)y * 8];
        u64 wl = el[(size_t)y * 8];
        int bp = (int)((wp >> lane) & 1ull);
        int bl = (int)((wl >> lane) & 1ull);
        k += bp; es += bl; ov += (bp & bl);
    }
    __shared__ int red[3][4][64];
    red[0][wave][lane] = k;
    red[1][wave][lane] = es;
    red[2][wave][lane] = ov;
    __syncthreads();
    if (threadIdx.x < 64) {
        int l = threadIdx.x;
        int K = red[0][0][l] + red[0][1][l] + red[0][2][l] + red[0][3][l];
        int E = red[1][0][l] + red[1][1][l] + red[1][2][l] + red[1][3][l];
        int O = red[2][0][l] + red[2][1][l] + red[2][2][l] + red[2][3][l];
        float logZ = logf(512.0f + 1.7182818284590452f * (float)K);
        float v = ((float)E * logZ - (float)O) * (1.0f / 4096.0f);
#pragma unroll
        for (int o = 32; o > 0; o >>= 1) v += __shfl_down(v, o, 64);
        if (l == 0) atomicAdd(out, v);
    }
}

// ---------------------------------------------------------------------------
extern "C" void kernel_launch(void* const* d_in, const int* in_sizes, int n_in,
                              void* d_out, int out_size, void* d_ws, size_t ws_size,
                              hipStream_t stream) {
    const float* pred = (const float*)d_in[0];
    const float* labels = (const float*)d_in[1];
    float* out = (float*)d_out;

    // workspace layout (bytes)
    u8*  imgs   = (u8*)d_ws;                                        // 16*HWSZ      = 4 MiB
    u16* magdir = (u16*)((char*)d_ws + (size_t)NIMG * HWSZ);        // 16*HWSZ*2    = 8 MiB
    u64* weak   = (u64*)((char*)d_ws + (size_t)NIMG * HWSZ * 3);    // 512 KiB
    u64* strong = (u64*)((char*)weak + (size_t)NIMG * HH * 8 * 8);  // 512 KiB
    u64* edges  = (u64*)((char*)strong + (size_t)NIMG * HH * 8 * 8);// 512 KiB

    hipLaunchKernelGGL(k_argmax, dim3(BB * HWSZ / 4 / 256), dim3(256), 0, stream,
                       pred, imgs);
    hipLaunchKernelGGL(k_imgl, dim3(BB * HWSZ / 4 / 256), dim3(256), 0, stream,
                       labels, imgs + (size_t)BB * HWSZ);
    hipLaunchKernelGGL(k_grad, dim3(NIMG * HH * 64 / 256), dim3(256), 0, stream,
                       imgs, magdir);
    hipLaunchKernelGGL(k_nms, dim3(NIMG * HWSZ / 256), dim3(256), 0, stream,
                       magdir, weak, strong);
    hipLaunchKernelGGL(k_hyst, dim3(NIMG), dim3(512), 0, stream,
                       weak, strong, edges);
    hipLaunchKernelGGL(k_zero, dim3(1), dim3(64), 0, stream, out);
    hipLaunchKernelGGL(k_loss, dim3(64), dim3(256), 0, stream, edges, out);
}